// Round 2
// baseline (25.380 us; speedup 1.0000x reference)
//
#include <hip/hip_runtime.h>
#include <math.h>

// Problem constants (from reference):
//   VOCAB=50257, D_MODEL=1024, BATCH=4, SEQ=4096
//   out[b,s,d] = emb_table[input_x[b,s], d] * 32.0f + pe[s,d]
//   pe[s,2j]   = sin(s * 10000^(-2j/1024))
//   pe[s,2j+1] = cos(s * 10000^(-2j/1024))
#define SEQ_LEN 4096
#define DMODEL  1024

__global__ __launch_bounds__(256) void TokenEmbedding_kernel(
    const int* __restrict__ tok,   // [B*S]
    const float* __restrict__ emb, // [VOCAB, D]
    float* __restrict__ out)       // [B*S, D]
{
    const int bs = blockIdx.x;              // flattened (b, s)
    const int s  = bs & (SEQ_LEN - 1);      // position within sequence
    const int t  = tok[bs];                 // block-uniform -> scalar load
    const int d0 = threadIdx.x << 2;        // 4 floats / thread, 256 thr = 1024

    const float4 e =
        *reinterpret_cast<const float4*>(emb + (long)t * DMODEL + d0);

    // Positional encoding, computed in REVOLUTIONS for v_sin/v_cos:
    //   rev_freq(i) = 10000^(-i/1024) / (2*pi)
    //               = exp2( -i * log2(10000)/1024 + log2(1/(2*pi)) )
    // then rev = fract(s * rev_freq); sin/cos via v_sin_f32/v_cos_f32
    // (ISA: input in revolutions; reduce with fract first).
    const float NEG_L2_10K_OVER_D = -13.287712379549609f / 1024.0f;
    const float L2_INV2PI         = -2.6514961294723187f; // log2(1/(2*pi))
    const float sp = (float)s;

    const float rf0 = __builtin_exp2f(fmaf((float)d0,       NEG_L2_10K_OVER_D, L2_INV2PI));
    const float rf1 = __builtin_exp2f(fmaf((float)(d0 + 2), NEG_L2_10K_OVER_D, L2_INV2PI));

    float r0 = sp * rf0; r0 -= floorf(r0);   // v_fract
    float r1 = sp * rf1; r1 -= floorf(r1);

#if __has_builtin(__builtin_amdgcn_sinf) && __has_builtin(__builtin_amdgcn_cosf)
    const float s0 = __builtin_amdgcn_sinf(r0);  // v_sin_f32: sin(r*2pi)
    const float c0 = __builtin_amdgcn_cosf(r0);
    const float s1 = __builtin_amdgcn_sinf(r1);
    const float c1 = __builtin_amdgcn_cosf(r1);
#else
    const float TWO_PI = 6.283185307179586f;
    const float s0 = sinf(r0 * TWO_PI), c0 = cosf(r0 * TWO_PI);
    const float s1 = sinf(r1 * TWO_PI), c1 = cosf(r1 * TWO_PI);
#endif

    float4 r;
    r.x = fmaf(e.x, 32.0f, s0);   // sqrt(1024) == 32 exactly
    r.y = fmaf(e.y, 32.0f, c0);
    r.z = fmaf(e.z, 32.0f, s1);
    r.w = fmaf(e.w, 32.0f, c1);

    *reinterpret_cast<float4*>(out + (long)bs * DMODEL + d0) = r;
}

extern "C" void kernel_launch(void* const* d_in, const int* in_sizes, int n_in,
                              void* d_out, int out_size, void* d_ws, size_t ws_size,
                              hipStream_t stream) {
    const int*   tok = (const int*)d_in[0];    // input_x, [4*4096] int32
    const float* emb = (const float*)d_in[1];  // emb_table, [50257*1024] f32
    float*       out = (float*)d_out;          // [4*4096*1024] f32

    const int n_tok = in_sizes[0];             // 16384 rows
    dim3 grid(n_tok), block(256);
    TokenEmbedding_kernel<<<grid, block, 0, stream>>>(tok, emb, out);
}

// Round 4
// 25.027 us; speedup vs baseline: 1.0141x; 1.0141x over previous
//
#include <hip/hip_runtime.h>
#include <math.h>

// Problem constants (from reference):
//   VOCAB=50257, D_MODEL=1024, BATCH=4, SEQ=4096
//   out[b,s,d] = emb_table[input_x[b,s], d] * 32.0f + pe[s,d]
//   pe[s,2j]   = sin(s * 10000^(-2j/1024))
//   pe[s,2j+1] = cos(s * 10000^(-2j/1024))
#define SEQ_LEN 4096
#define DMODEL  1024

typedef float f32x4 __attribute__((ext_vector_type(4)));

__global__ __launch_bounds__(256) void TokenEmbedding_kernel(
    const int* __restrict__ tok,   // [B*S]
    const float* __restrict__ emb, // [VOCAB, D]
    float* __restrict__ out)       // [B*S, D]
{
    const int bs = blockIdx.x;              // flattened (b, s)
    const int s  = bs & (SEQ_LEN - 1);      // position within sequence
    const int t  = tok[bs];                 // block-uniform -> scalar load
    const int d0 = threadIdx.x << 2;        // 4 floats / thread, 256 thr = 1024

    const f32x4 e =
        *reinterpret_cast<const f32x4*>(emb + (long)t * DMODEL + d0);

    // Positional encoding, computed in REVOLUTIONS for v_sin/v_cos:
    //   rev_freq(i) = 10000^(-i/1024) / (2*pi)
    //               = exp2( -i * log2(10000)/1024 + log2(1/(2*pi)) )
    // then rev = fract(s * rev_freq); sin/cos via v_sin_f32/v_cos_f32
    // (ISA: input in revolutions; reduce with fract first).
    const float NEG_L2_10K_OVER_D = -13.287712379549609f / 1024.0f;
    const float L2_INV2PI         = -2.6514961294723187f; // log2(1/(2*pi))
    const float sp = (float)s;

    const float rf0 = __builtin_exp2f(fmaf((float)d0,       NEG_L2_10K_OVER_D, L2_INV2PI));
    const float rf1 = __builtin_exp2f(fmaf((float)(d0 + 2), NEG_L2_10K_OVER_D, L2_INV2PI));

    float r0 = sp * rf0; r0 -= floorf(r0);   // v_fract
    float r1 = sp * rf1; r1 -= floorf(r1);

#if __has_builtin(__builtin_amdgcn_sinf) && __has_builtin(__builtin_amdgcn_cosf)
    const float s0 = __builtin_amdgcn_sinf(r0);  // v_sin_f32: sin(r*2pi)
    const float c0 = __builtin_amdgcn_cosf(r0);
    const float s1 = __builtin_amdgcn_sinf(r1);
    const float c1 = __builtin_amdgcn_cosf(r1);
#else
    const float TWO_PI = 6.283185307179586f;
    const float s0 = sinf(r0 * TWO_PI), c0 = cosf(r0 * TWO_PI);
    const float s1 = sinf(r1 * TWO_PI), c1 = cosf(r1 * TWO_PI);
#endif

    f32x4 r;
    r.x = fmaf(e.x, 32.0f, s0);   // sqrt(1024) == 32 exactly
    r.y = fmaf(e.y, 32.0f, c0);
    r.z = fmaf(e.z, 32.0f, s1);
    r.w = fmaf(e.w, 32.0f, c1);

    // Output is write-once, never re-read by this kernel: non-temporal store
    // (MUBUF `nt`) — avoids RFO and keeps L2/L3 lines for the embedding table.
    __builtin_nontemporal_store(
        r, reinterpret_cast<f32x4*>(out + (long)bs * DMODEL + d0));
}

extern "C" void kernel_launch(void* const* d_in, const int* in_sizes, int n_in,
                              void* d_out, int out_size, void* d_ws, size_t ws_size,
                              hipStream_t stream) {
    const int*   tok = (const int*)d_in[0];    // input_x, [4*4096] int32
    const float* emb = (const float*)d_in[1];  // emb_table, [50257*1024] f32
    float*       out = (float*)d_out;          // [4*4096*1024] f32

    const int n_tok = in_sizes[0];             // 16384 rows
    dim3 grid(n_tok), block(256);
    TokenEmbedding_kernel<<<grid, block, 0, stream>>>(tok, emb, out);
}